// Round 2
// baseline (854.448 us; speedup 1.0000x reference)
//
#include <hip/hip_runtime.h>

// Soft differentiable rasterizer, forward only.
// out[t,h,w,c] = composite over z-sorted soft 12-gons.
//
// Restructurings vs reference:
//  * cov = prod sigmoid(s_k) = 1 / prod(1 + exp(-s_k))  -> one rcp per prim.
//  * per-edge affine u = nax*gy + nay*gx + nb with orient/SOFT/log2e folded in,
//    evaluated as 2 FMA + max + 1 v_exp_f32 per edge.
//  * exclusive reverse cumprod == front-to-back transmittance loop (O(1) state).
//  * per-frame prim data precomputed once per block into LDS, already in
//    front-to-back slot order, colors pre-multiplied by (1 - csg).
//
// R1 fix: clamp u >= -100 before exp2. Without it, one edge giving
// eu = exp2(+280) = inf (p -> inf, legitimately "cov = 0") plus another edge
// giving eu = exp2(-280) = 0 produced fmaf(inf, 0, inf) = NaN.

#define HH 128
#define WW 128
#define NN 128
#define KK 12
#define TPB 256
#define STATE_SZ (NN * KK * 2 + NN) // 3200

__global__ __launch_bounds__(TPB) void raster_kernel(
    const float* __restrict__ traj,    // [T,1,3200]
    const float* __restrict__ colors,  // [1,N,3]
    const float* __restrict__ alpha,   // [N]
    const float* __restrict__ zval,    // [N]
    const void*  __restrict__ csg_raw, // [N] layout auto-detected
    float* __restrict__ out)           // [T,H,W,3]
{
    __shared__ __align__(16) float s_coef[NN][3 * KK]; // 18 KB, slot-ordered
    __shared__ __align__(16) float s_gc[NN][4];        // {g, r', g', b'} per slot
    __shared__ float s_state[STATE_SZ];                // 12.8 KB
    __shared__ float s_orient[NN];
    __shared__ float s_z[NN];
    __shared__ int   s_slot2prim[NN];
    __shared__ int   s_mode;

    const int frame = blockIdx.y;
    const int tid   = threadIdx.x;
    const float* st = traj + (size_t)frame * STATE_SZ;

    // ---- Phase 1: stage state + z, detect csg layout ----
    for (int i = tid; i < STATE_SZ; i += TPB) s_state[i] = st[i];
    if (tid < NN) s_z[tid] = zval[tid];
    if (tid == 0) {
        // bool (1B), int32, or float32 storage for csg? detect from raw bytes.
        const unsigned char* b = (const unsigned char*)csg_raw;
        const unsigned int*  w = (const unsigned int*)csg_raw;
        int mode = 0; // int32
        bool words01 = true;
        for (int i = 0; i < 32; i++) if (w[i] > 1u) { words01 = false; break; }
        if (!words01) {
            bool bytes01 = true;
            for (int i = 0; i < 128; i++) if (b[i] > 1) { bytes01 = false; break; }
            mode = bytes01 ? 1 : 2; // 1 = byte, 2 = float
        }
        s_mode = mode;
    }
    __syncthreads();

    // ---- Phase 2: per-prim orient, g = alpha*sigmoid(alive), z-rank -> slot ----
    if (tid < NN) {
        const int n = tid;
        float area2 = 0.f;
        #pragma unroll
        for (int k = 0; k < KK; k++) {
            int k1 = (k + 1) % KK;
            float v0x = s_state[(n * KK + k)  * 2 + 0];
            float v0y = s_state[(n * KK + k)  * 2 + 1];
            float v1x = s_state[(n * KK + k1) * 2 + 0];
            float v1y = s_state[(n * KK + k1) * 2 + 1];
            area2 += v0x * v1y - v1x * v0y;
        }
        float orient = (area2 > 0.f) ? 1.f : ((area2 < 0.f) ? -1.f : 0.f);
        s_orient[n] = orient;

        float alive = s_state[NN * KK * 2 + n];
        float g = alpha[n] / (1.f + __expf(-alive));

        // stable rank of z[n] ascending; slot 0 = frontmost (largest z)
        float zn = s_z[n];
        int rank = 0;
        for (int j = 0; j < NN; j++) {
            float zj = s_z[j];
            rank += (zj < zn || (zj == zn && j < n)) ? 1 : 0;
        }
        int slot = (NN - 1) - rank;
        s_slot2prim[slot] = n;

        int mode = s_mode;
        int sub;
        if (mode == 0)      sub = ((const int*)csg_raw)[n] != 0;
        else if (mode == 1) sub = ((const unsigned char*)csg_raw)[n] != 0;
        else                sub = ((const float*)csg_raw)[n] != 0.f;
        float cs = sub ? 0.f : 1.f;
        s_gc[slot][0] = g;
        s_gc[slot][1] = colors[n * 3 + 0] * cs;
        s_gc[slot][2] = colors[n * 3 + 1] * cs;
        s_gc[slot][3] = colors[n * 3 + 2] * cs;
    }
    __syncthreads();

    // ---- Phase 3: per-edge affine coefficients, slot-ordered ----
    // u = -s*orient/SOFT*log2(e) = nax*gy + nay*gx + nb ; sigmoid = 1/(1+2^u)
    const float QSCALE = 100.0f * 1.4426950408889634f; // (1/SOFT)*log2(e)
    for (int idx = tid; idx < NN * KK; idx += TPB) {
        int slot = idx / KK;
        int k    = idx - slot * KK;
        int n    = s_slot2prim[slot];
        int k1   = (k + 1) % KK;
        float v0x = s_state[(n * KK + k)  * 2 + 0];
        float v0y = s_state[(n * KK + k)  * 2 + 1];
        float v1x = s_state[(n * KK + k1) * 2 + 0];
        float v1y = s_state[(n * KK + k1) * 2 + 1];
        float ex = v1x - v0x, ey = v1y - v0y;
        float q  = -s_orient[n] * QSCALE;
        s_coef[slot][k * 3 + 0] = q * ex;                       // coeff of gy
        s_coef[slot][k * 3 + 1] = -q * ey;                      // coeff of gx
        s_coef[slot][k * 3 + 2] = -q * (ex * v0y - ey * v0x);   // constant
    }
    __syncthreads();

    // ---- Main: one pixel per thread, front-to-back composite ----
    const int p_idx = blockIdx.x * TPB + tid;
    const int h = p_idx >> 7;
    const int w = p_idx & (WW - 1);
    const float gy = (h + 0.5f) * (1.0f / HH);
    const float gx = (w + 0.5f) * (1.0f / WW);

    float Tt = 1.f, rr = 0.f, gg = 0.f, bb = 0.f;
    for (int slot = 0; slot < NN; slot++) {
        float cf[3 * KK];
        const float4* cp = (const float4*)&s_coef[slot][0];
        #pragma unroll
        for (int i = 0; i < 9; i++) ((float4*)cf)[i] = cp[i]; // ds_read_b128 x9

        float p = 1.f;
        #pragma unroll
        for (int k = 0; k < KK; k++) {
            float u  = fmaf(cf[3 * k + 0], gy, fmaf(cf[3 * k + 1], gx, cf[3 * k + 2]));
            u = fmaxf(u, -100.0f);             // forbid exp2 underflow to 0 (inf*0=NaN)
            float eu = __builtin_amdgcn_exp2f(u);
            p = fmaf(p, eu, p); // p *= (1 + 2^u); overflow->inf->cov=0, correct
        }
        float cov = __builtin_amdgcn_rcpf(p);

        float4 gc = *(const float4*)&s_gc[slot][0];
        float a   = cov * gc.x;
        float wgt = a * Tt;
        rr = fmaf(wgt, gc.y, rr);
        gg = fmaf(wgt, gc.z, gg);
        bb = fmaf(wgt, gc.w, bb);
        Tt = fmaf(-a, Tt, Tt); // T *= (1 - a)
    }

    size_t o = ((size_t)frame * (HH * WW) + p_idx) * 3;
    out[o + 0] = rr;
    out[o + 1] = gg;
    out[o + 2] = bb;
}

extern "C" void kernel_launch(void* const* d_in, const int* in_sizes, int n_in,
                              void* d_out, int out_size, void* d_ws, size_t ws_size,
                              hipStream_t stream) {
    const float* traj   = (const float*)d_in[0];
    const float* colors = (const float*)d_in[1];
    const float* alpha  = (const float*)d_in[2];
    const float* zval   = (const float*)d_in[3];
    const void*  csg    = d_in[4];
    float* out = (float*)d_out;

    const int T = in_sizes[0] / STATE_SZ; // 192
    dim3 grid((HH * WW) / TPB, T);        // 64 x 192
    raster_kernel<<<grid, TPB, 0, stream>>>(traj, colors, alpha, zval, csg, out);
}

// Round 3
// 731.611 us; speedup vs baseline: 1.1679x; 1.1679x over previous
//
#include <hip/hip_runtime.h>

// Soft differentiable rasterizer, forward only.
// R2 -> R3 changes (VALU+LDS-pipe bound per rocprof: VALUBusy~113%, HBM 0.65%):
//  * 2 pixels/thread (same row): halves LDS broadcast traffic per pixel;
//    second pixel's edge value u1 = u0 + B*dx (one extra FMA, not a new chain).
//  * packed fp32 (v_pk_fma_f32 / v_pk_max_f32) over edge PAIRS via
//    ext_vector_type(2) + __builtin_elementwise_*.
//  * wave-coherent early exit when every lane's transmittance T < 1e-3:
//    remaining contribution bounded by T_exit = 1e-3 < threshold margin.
//  * coefficient layout per slot: SoA [A[12] | B[12] | C[12] | gc[4]] = 40 floats,
//    10x ds_read_b128 broadcast per slot-wave.

#define HH 128
#define WW 128
#define NN 128
#define KK 12
#define TPB 256
#define STATE_SZ (NN * KK * 2 + NN) // 3200
#define PX_PER_THREAD 2

typedef float f2 __attribute__((ext_vector_type(2)));

__global__ __launch_bounds__(TPB) void raster_kernel(
    const float* __restrict__ traj,    // [T,1,3200]
    const float* __restrict__ colors,  // [1,N,3]
    const float* __restrict__ alpha,   // [N]
    const float* __restrict__ zval,    // [N]
    const void*  __restrict__ csg_raw, // [N] layout auto-detected
    float* __restrict__ out)           // [T,H,W,3]
{
    __shared__ __align__(16) float s_coef[NN][40]; // 20.5 KB, slot-ordered SoA
    __shared__ float s_state[STATE_SZ];            // 12.8 KB
    __shared__ float s_orient[NN];
    __shared__ float s_z[NN];
    __shared__ int   s_slot2prim[NN];
    __shared__ int   s_mode;

    const int frame = blockIdx.y;
    const int tid   = threadIdx.x;
    const float* st = traj + (size_t)frame * STATE_SZ;

    // ---- Phase 1: stage state + z, detect csg layout ----
    for (int i = tid; i < STATE_SZ; i += TPB) s_state[i] = st[i];
    if (tid < NN) s_z[tid] = zval[tid];
    if (tid == 0) {
        const unsigned char* b = (const unsigned char*)csg_raw;
        const unsigned int*  w = (const unsigned int*)csg_raw;
        int mode = 0; // int32
        bool words01 = true;
        for (int i = 0; i < 32; i++) if (w[i] > 1u) { words01 = false; break; }
        if (!words01) {
            bool bytes01 = true;
            for (int i = 0; i < 128; i++) if (b[i] > 1) { bytes01 = false; break; }
            mode = bytes01 ? 1 : 2; // 1 = byte, 2 = float
        }
        s_mode = mode;
    }
    __syncthreads();

    // ---- Phase 2: per-prim orient, g = alpha*sigmoid(alive), z-rank -> slot ----
    if (tid < NN) {
        const int n = tid;
        float area2 = 0.f;
        #pragma unroll
        for (int k = 0; k < KK; k++) {
            int k1 = (k + 1) % KK;
            float v0x = s_state[(n * KK + k)  * 2 + 0];
            float v0y = s_state[(n * KK + k)  * 2 + 1];
            float v1x = s_state[(n * KK + k1) * 2 + 0];
            float v1y = s_state[(n * KK + k1) * 2 + 1];
            area2 += v0x * v1y - v1x * v0y;
        }
        float orient = (area2 > 0.f) ? 1.f : ((area2 < 0.f) ? -1.f : 0.f);
        s_orient[n] = orient;

        float alive = s_state[NN * KK * 2 + n];
        float g = alpha[n] / (1.f + __expf(-alive));

        // stable rank of z[n] ascending; slot 0 = frontmost (largest z)
        float zn = s_z[n];
        int rank = 0;
        for (int j = 0; j < NN; j++) {
            float zj = s_z[j];
            rank += (zj < zn || (zj == zn && j < n)) ? 1 : 0;
        }
        int slot = (NN - 1) - rank;
        s_slot2prim[slot] = n;

        int mode = s_mode;
        int sub;
        if (mode == 0)      sub = ((const int*)csg_raw)[n] != 0;
        else if (mode == 1) sub = ((const unsigned char*)csg_raw)[n] != 0;
        else                sub = ((const float*)csg_raw)[n] != 0.f;
        float cs = sub ? 0.f : 1.f;
        s_coef[slot][36] = g;
        s_coef[slot][37] = colors[n * 3 + 0] * cs;
        s_coef[slot][38] = colors[n * 3 + 1] * cs;
        s_coef[slot][39] = colors[n * 3 + 2] * cs;
    }
    __syncthreads();

    // ---- Phase 3: per-edge affine coefficients, slot-ordered, SoA ----
    // u = -s*orient/SOFT*log2(e) = A*gy + B*gx + C ; sigmoid = 1/(1+2^u)
    const float QSCALE = 100.0f * 1.4426950408889634f; // (1/SOFT)*log2(e)
    for (int idx = tid; idx < NN * KK; idx += TPB) {
        int slot = idx / KK;
        int k    = idx - slot * KK;
        int n    = s_slot2prim[slot];
        int k1   = (k + 1) % KK;
        float v0x = s_state[(n * KK + k)  * 2 + 0];
        float v0y = s_state[(n * KK + k)  * 2 + 1];
        float v1x = s_state[(n * KK + k1) * 2 + 0];
        float v1y = s_state[(n * KK + k1) * 2 + 1];
        float ex = v1x - v0x, ey = v1y - v0y;
        float q  = -s_orient[n] * QSCALE;
        s_coef[slot][0  + k] = q * ex;                      // A: coeff of gy
        s_coef[slot][12 + k] = -q * ey;                     // B: coeff of gx
        s_coef[slot][24 + k] = -q * (ex * v0y - ey * v0x);  // C: constant
    }
    __syncthreads();

    // ---- Main: two pixels (same row) per thread, front-to-back composite ----
    const int p0 = (blockIdx.x * TPB + tid) * PX_PER_THREAD;
    const int h  = p0 >> 7;
    const float gy = (h + 0.5f) * (1.0f / HH);
    const float gx = ((p0 & (WW - 1)) + 0.5f) * (1.0f / WW);
    const f2 gyv = {gy, gy};
    const f2 gxv = {gx, gx};
    const f2 dxv = {1.0f / WW, 1.0f / WW};   // pixel1 = pixel0 + dx
    const f2 loV = {-100.f, -100.f};

    float T0 = 1.f, T1 = 1.f;
    float r0 = 0.f, g0 = 0.f, b0 = 0.f;
    float r1 = 0.f, g1 = 0.f, b1 = 0.f;

    for (int slot = 0; slot < NN; slot++) {
        float cf[40];
        const float4* cp = (const float4*)&s_coef[slot][0];
        #pragma unroll
        for (int i = 0; i < 10; i++) ((float4*)cf)[i] = cp[i]; // ds_read_b128 x10

        const f2* Ap = (const f2*)&cf[0];
        const f2* Bp = (const f2*)&cf[12];
        const f2* Cp = (const f2*)&cf[24];

        f2 q0 = {1.f, 1.f}, q1 = {1.f, 1.f};
        #pragma unroll
        for (int j = 0; j < 6; j++) {
            f2 u0 = __builtin_elementwise_fma(Ap[j], gyv,
                      __builtin_elementwise_fma(Bp[j], gxv, Cp[j]));
            f2 u1 = __builtin_elementwise_fma(Bp[j], dxv, u0); // next pixel in row
            u0 = __builtin_elementwise_max(u0, loV); // forbid exp2 underflow (inf*0=NaN)
            u1 = __builtin_elementwise_max(u1, loV);
            f2 e0, e1;
            e0.x = __builtin_amdgcn_exp2f(u0.x);
            e0.y = __builtin_amdgcn_exp2f(u0.y);
            e1.x = __builtin_amdgcn_exp2f(u1.x);
            e1.y = __builtin_amdgcn_exp2f(u1.y);
            q0 = __builtin_elementwise_fma(q0, e0, q0); // q *= (1 + 2^u)
            q1 = __builtin_elementwise_fma(q1, e1, q1);
        }
        float cov0 = __builtin_amdgcn_rcpf(q0.x * q0.y);
        float cov1 = __builtin_amdgcn_rcpf(q1.x * q1.y);

        float gA = cf[36], cr = cf[37], cg = cf[38], cb = cf[39];
        float a0 = cov0 * gA, a1 = cov1 * gA;
        float w0 = a0 * T0,   w1 = a1 * T1;
        r0 = fmaf(w0, cr, r0);  r1 = fmaf(w1, cr, r1);
        g0 = fmaf(w0, cg, g0);  g1 = fmaf(w1, cg, g1);
        b0 = fmaf(w0, cb, b0);  b1 = fmaf(w1, cb, b1);
        T0 = fmaf(-a0, T0, T0); T1 = fmaf(-a1, T1, T1);

        // wave-coherent early exit: residual contribution <= T < 1e-3
        if (!__any(fmaxf(T0, T1) > 1e-3f)) break;
    }

    size_t o = ((size_t)frame * (HH * WW) + p0) * 3; // 24B per thread, 8-aligned
    float2* op = (float2*)(out + o);
    op[0] = make_float2(r0, g0);
    op[1] = make_float2(b0, r1);
    op[2] = make_float2(g1, b1);
}

extern "C" void kernel_launch(void* const* d_in, const int* in_sizes, int n_in,
                              void* d_out, int out_size, void* d_ws, size_t ws_size,
                              hipStream_t stream) {
    const float* traj   = (const float*)d_in[0];
    const float* colors = (const float*)d_in[1];
    const float* alpha  = (const float*)d_in[2];
    const float* zval   = (const float*)d_in[3];
    const void*  csg    = d_in[4];
    float* out = (float*)d_out;

    const int T = in_sizes[0] / STATE_SZ; // 192
    dim3 grid((HH * WW) / (TPB * PX_PER_THREAD), T); // 32 x 192
    raster_kernel<<<grid, TPB, 0, stream>>>(traj, colors, alpha, zval, csg, out);
}

// Round 4
// 664.687 us; speedup vs baseline: 1.2855x; 1.1007x over previous
//
#include <hip/hip_runtime.h>

// Soft differentiable rasterizer, forward only.
// R3 -> R4 (VALU-issue bound, early-exit ineffective): per-ROW primitive
// culling. cov(px) <= 2^{-u_k(px)} for every edge; u_k affine in gx so its
// row-min is A*gy + C + min(B*gx_lo, B*gx_hi). If max_k rowmin(u_k) >= 20,
// the primitive contributes <= 2^-20 per pixel on this row -> cull.
// Survivors are stable-compacted per row (z order preserved); each wave owns
// one row so the compacted list is wave-uniform. Slot index prefetched one
// iteration ahead to hide ds_read latency.

#define HH 128
#define WW 128
#define NN 128
#define KK 12
#define TPB 256
#define STATE_SZ (NN * KK * 2 + NN) // 3200
#define ROWS_PER_BLOCK 4
#define CULL_U 20.0f

typedef float f2 __attribute__((ext_vector_type(2)));

__global__ __launch_bounds__(TPB) void raster_kernel(
    const float* __restrict__ traj,    // [T,1,3200]
    const float* __restrict__ colors,  // [1,N,3]
    const float* __restrict__ alpha,   // [N]
    const float* __restrict__ zval,    // [N]
    const void*  __restrict__ csg_raw, // [N] layout auto-detected
    float* __restrict__ out)           // [T,H,W,3]
{
    __shared__ __align__(16) float s_coef[NN][40]; // 20.5 KB, slot-ordered SoA
    __shared__ float s_state[STATE_SZ];            // 12.8 KB
    __shared__ float s_orient[NN];
    __shared__ float s_z[NN];
    __shared__ int   s_slot2prim[NN];
    __shared__ unsigned char s_keep[ROWS_PER_BLOCK][NN];
    __shared__ unsigned char s_list[ROWS_PER_BLOCK][NN + 4];
    __shared__ int   s_cnt[ROWS_PER_BLOCK];
    __shared__ int   s_mode;

    const int frame = blockIdx.y;
    const int tid   = threadIdx.x;
    const int row0  = blockIdx.x * ROWS_PER_BLOCK;
    const float* st = traj + (size_t)frame * STATE_SZ;

    // ---- Phase 1: stage state + z, detect csg layout ----
    for (int i = tid; i < STATE_SZ; i += TPB) s_state[i] = st[i];
    if (tid < NN) s_z[tid] = zval[tid];
    if (tid == 0) {
        const unsigned char* b = (const unsigned char*)csg_raw;
        const unsigned int*  w = (const unsigned int*)csg_raw;
        int mode = 0; // int32
        bool words01 = true;
        for (int i = 0; i < 32; i++) if (w[i] > 1u) { words01 = false; break; }
        if (!words01) {
            bool bytes01 = true;
            for (int i = 0; i < 128; i++) if (b[i] > 1) { bytes01 = false; break; }
            mode = bytes01 ? 1 : 2; // 1 = byte, 2 = float
        }
        s_mode = mode;
    }
    __syncthreads();

    // ---- Phase 2: per-prim orient, g = alpha*sigmoid(alive), z-rank -> slot ----
    if (tid < NN) {
        const int n = tid;
        float area2 = 0.f;
        #pragma unroll
        for (int k = 0; k < KK; k++) {
            int k1 = (k + 1) % KK;
            float v0x = s_state[(n * KK + k)  * 2 + 0];
            float v0y = s_state[(n * KK + k)  * 2 + 1];
            float v1x = s_state[(n * KK + k1) * 2 + 0];
            float v1y = s_state[(n * KK + k1) * 2 + 1];
            area2 += v0x * v1y - v1x * v0y;
        }
        float orient = (area2 > 0.f) ? 1.f : ((area2 < 0.f) ? -1.f : 0.f);
        s_orient[n] = orient;

        float alive = s_state[NN * KK * 2 + n];
        float g = alpha[n] / (1.f + __expf(-alive));

        // stable rank of z[n] ascending; slot 0 = frontmost (largest z)
        float zn = s_z[n];
        int rank = 0;
        for (int j = 0; j < NN; j++) {
            float zj = s_z[j];
            rank += (zj < zn || (zj == zn && j < n)) ? 1 : 0;
        }
        int slot = (NN - 1) - rank;
        s_slot2prim[slot] = n;

        int mode = s_mode;
        int sub;
        if (mode == 0)      sub = ((const int*)csg_raw)[n] != 0;
        else if (mode == 1) sub = ((const unsigned char*)csg_raw)[n] != 0;
        else                sub = ((const float*)csg_raw)[n] != 0.f;
        float cs = sub ? 0.f : 1.f;
        s_coef[slot][36] = g;
        s_coef[slot][37] = colors[n * 3 + 0] * cs;
        s_coef[slot][38] = colors[n * 3 + 1] * cs;
        s_coef[slot][39] = colors[n * 3 + 2] * cs;
    }
    __syncthreads();

    // ---- Phase 3: per-edge affine coefficients, slot-ordered, SoA ----
    // u = -s*orient/SOFT*log2(e) = A*gy + B*gx + C ; sigmoid = 1/(1+2^u)
    const float QSCALE = 100.0f * 1.4426950408889634f; // (1/SOFT)*log2(e)
    for (int idx = tid; idx < NN * KK; idx += TPB) {
        int slot = idx / KK;
        int k    = idx - slot * KK;
        int n    = s_slot2prim[slot];
        int k1   = (k + 1) % KK;
        float v0x = s_state[(n * KK + k)  * 2 + 0];
        float v0y = s_state[(n * KK + k)  * 2 + 1];
        float v1x = s_state[(n * KK + k1) * 2 + 0];
        float v1y = s_state[(n * KK + k1) * 2 + 1];
        float ex = v1x - v0x, ey = v1y - v0y;
        float q  = -s_orient[n] * QSCALE;
        s_coef[slot][0  + k] = q * ex;                      // A: coeff of gy
        s_coef[slot][12 + k] = -q * ey;                     // B: coeff of gx
        s_coef[slot][24 + k] = -q * (ex * v0y - ey * v0x);  // C: constant
    }
    __syncthreads();

    // ---- Phase 3.5a: per-(row, slot) cull test ----
    const float GX_LO = 0.5f / WW;
    const float GX_HI = (WW - 0.5f) / WW;
    for (int idx = tid; idx < ROWS_PER_BLOCK * NN; idx += TPB) {
        int r = idx >> 7;
        int s = idx & (NN - 1);
        float gyr = (row0 + r + 0.5f) * (1.0f / HH);
        float umax = -1e30f;
        #pragma unroll
        for (int k = 0; k < KK; k++) {
            float A = s_coef[s][k];
            float B = s_coef[s][12 + k];
            float C = s_coef[s][24 + k];
            float base = fmaf(A, gyr, C);
            float t0 = fmaf(B, GX_LO, base);
            float t1 = fmaf(B, GX_HI, base);
            umax = fmaxf(umax, fminf(t0, t1)); // row-min of u_k, max over k
        }
        s_keep[r][s] = (umax < CULL_U) ? 1 : 0;
    }
    __syncthreads();

    // ---- Phase 3.5b: stable compaction, one wave per row (z order kept) ----
    {
        const int wv = tid >> 6, ln = tid & 63;
        int base = 0;
        #pragma unroll
        for (int half = 0; half < 2; half++) {
            int s = half * 64 + ln;
            bool k = s_keep[wv][s] != 0;
            unsigned long long m = __ballot(k);
            int pre = __popcll(m & ((1ull << ln) - 1ull));
            if (k) s_list[wv][base + pre] = (unsigned char)s;
            base += __popcll(m);
        }
        if (ln == 0) s_cnt[wv] = base;
    }
    __syncthreads();

    // ---- Main: two pixels (same row) per thread; wave = one row ----
    const int wv   = tid >> 6;
    const int lane = tid & 63;
    const int row  = row0 + wv;
    const int px0  = lane * 2;
    const float gy = (row + 0.5f) * (1.0f / HH);
    const float gx = (px0 + 0.5f) * (1.0f / WW);
    const f2 gyv = {gy, gy};
    const f2 gxv = {gx, gx};
    const f2 dxv = {1.0f / WW, 1.0f / WW};
    const f2 loV = {-100.f, -100.f};

    float T0 = 1.f, T1 = 1.f;
    float r0 = 0.f, g0 = 0.f, b0 = 0.f;
    float r1 = 0.f, g1 = 0.f, b1 = 0.f;

    const int cnt = s_cnt[wv];
    int slot = (cnt > 0) ? (int)s_list[wv][0] : 0;
    for (int i = 0; i < cnt; i++) {
        int nslot = (int)s_list[wv][i + 1]; // prefetch (padded array; unused on last iter)

        float cf[40];
        const float4* cp = (const float4*)&s_coef[slot][0];
        #pragma unroll
        for (int i4 = 0; i4 < 10; i4++) ((float4*)cf)[i4] = cp[i4]; // ds_read_b128 x10

        const f2* Ap = (const f2*)&cf[0];
        const f2* Bp = (const f2*)&cf[12];
        const f2* Cp = (const f2*)&cf[24];

        f2 q0 = {1.f, 1.f}, q1 = {1.f, 1.f};
        #pragma unroll
        for (int j = 0; j < 6; j++) {
            f2 u0 = __builtin_elementwise_fma(Ap[j], gyv,
                      __builtin_elementwise_fma(Bp[j], gxv, Cp[j]));
            f2 u1 = __builtin_elementwise_fma(Bp[j], dxv, u0); // next pixel in row
            u0 = __builtin_elementwise_max(u0, loV); // forbid exp2 underflow (inf*0=NaN)
            u1 = __builtin_elementwise_max(u1, loV);
            f2 e0, e1;
            e0.x = __builtin_amdgcn_exp2f(u0.x);
            e0.y = __builtin_amdgcn_exp2f(u0.y);
            e1.x = __builtin_amdgcn_exp2f(u1.x);
            e1.y = __builtin_amdgcn_exp2f(u1.y);
            q0 = __builtin_elementwise_fma(q0, e0, q0); // q *= (1 + 2^u)
            q1 = __builtin_elementwise_fma(q1, e1, q1);
        }
        float cov0 = __builtin_amdgcn_rcpf(q0.x * q0.y);
        float cov1 = __builtin_amdgcn_rcpf(q1.x * q1.y);

        float gA = cf[36], cr = cf[37], cg = cf[38], cb = cf[39];
        float a0 = cov0 * gA, a1 = cov1 * gA;
        float w0 = a0 * T0,   w1 = a1 * T1;
        r0 = fmaf(w0, cr, r0);  r1 = fmaf(w1, cr, r1);
        g0 = fmaf(w0, cg, g0);  g1 = fmaf(w1, cg, g1);
        b0 = fmaf(w0, cb, b0);  b1 = fmaf(w1, cb, b1);
        T0 = fmaf(-a0, T0, T0); T1 = fmaf(-a1, T1, T1);

        slot = nslot;
        // wave-coherent early exit: residual contribution <= T < 1e-3
        if (!__any(fmaxf(T0, T1) > 1e-3f)) break;
    }

    size_t o = ((size_t)frame * (HH * WW) + (size_t)row * WW + px0) * 3;
    float2* op = (float2*)(out + o);
    op[0] = make_float2(r0, g0);
    op[1] = make_float2(b0, r1);
    op[2] = make_float2(g1, b1);
}

extern "C" void kernel_launch(void* const* d_in, const int* in_sizes, int n_in,
                              void* d_out, int out_size, void* d_ws, size_t ws_size,
                              hipStream_t stream) {
    const float* traj   = (const float*)d_in[0];
    const float* colors = (const float*)d_in[1];
    const float* alpha  = (const float*)d_in[2];
    const float* zval   = (const float*)d_in[3];
    const void*  csg    = d_in[4];
    float* out = (float*)d_out;

    const int T = in_sizes[0] / STATE_SZ; // 192
    dim3 grid(HH / ROWS_PER_BLOCK, T);    // 32 x 192
    raster_kernel<<<grid, TPB, 0, stream>>>(traj, colors, alpha, zval, csg, out);
}

// Round 5
// 563.507 us; speedup vs baseline: 1.5163x; 1.1796x over previous
//
#include <hip/hip_runtime.h>

// Soft differentiable rasterizer, forward only.
// R4 -> R5: JOINT interval cull. Each edge's u_k = B*gx + (A*gy + C) < U is a
// half-line constraint in gx; intersecting all 12 yields [xlo,xhi]. Empty
// intersection with the row's x-range => cov < 2^-U everywhere on the row =>
// cull. This subsumes R4's per-edge test (which only fired when ONE edge
// excluded the whole row) and should collapse the survivor count, since a
// random self-intersecting 12-gon's soft convex kernel is typically tiny/empty.
// Conservative: rcp err << SLACK widening; NaN/zero-B cases fall on "keep".

#define HH 128
#define WW 128
#define NN 128
#define KK 12
#define TPB 256
#define STATE_SZ (NN * KK * 2 + NN) // 3200
#define ROWS_PER_BLOCK 4
#define CULL_U 20.0f

typedef float f2 __attribute__((ext_vector_type(2)));

__global__ __launch_bounds__(TPB) void raster_kernel(
    const float* __restrict__ traj,    // [T,1,3200]
    const float* __restrict__ colors,  // [1,N,3]
    const float* __restrict__ alpha,   // [N]
    const float* __restrict__ zval,    // [N]
    const void*  __restrict__ csg_raw, // [N] layout auto-detected
    float* __restrict__ out)           // [T,H,W,3]
{
    __shared__ __align__(16) float s_coef[NN][40]; // 20.5 KB, slot-ordered SoA
    __shared__ float s_state[STATE_SZ];            // 12.8 KB
    __shared__ float s_orient[NN];
    __shared__ float s_z[NN];
    __shared__ int   s_slot2prim[NN];
    __shared__ unsigned char s_keep[ROWS_PER_BLOCK][NN];
    __shared__ unsigned char s_list[ROWS_PER_BLOCK][NN + 4];
    __shared__ int   s_cnt[ROWS_PER_BLOCK];
    __shared__ int   s_mode;

    const int frame = blockIdx.y;
    const int tid   = threadIdx.x;
    const int row0  = blockIdx.x * ROWS_PER_BLOCK;
    const float* st = traj + (size_t)frame * STATE_SZ;

    // ---- Phase 1: stage state + z, detect csg layout ----
    for (int i = tid; i < STATE_SZ; i += TPB) s_state[i] = st[i];
    if (tid < NN) s_z[tid] = zval[tid];
    if (tid == 0) {
        const unsigned char* b = (const unsigned char*)csg_raw;
        const unsigned int*  w = (const unsigned int*)csg_raw;
        int mode = 0; // int32
        bool words01 = true;
        for (int i = 0; i < 32; i++) if (w[i] > 1u) { words01 = false; break; }
        if (!words01) {
            bool bytes01 = true;
            for (int i = 0; i < 128; i++) if (b[i] > 1) { bytes01 = false; break; }
            mode = bytes01 ? 1 : 2; // 1 = byte, 2 = float
        }
        s_mode = mode;
    }
    __syncthreads();

    // ---- Phase 2: per-prim orient, g = alpha*sigmoid(alive), z-rank -> slot ----
    if (tid < NN) {
        const int n = tid;
        float area2 = 0.f;
        #pragma unroll
        for (int k = 0; k < KK; k++) {
            int k1 = (k + 1) % KK;
            float v0x = s_state[(n * KK + k)  * 2 + 0];
            float v0y = s_state[(n * KK + k)  * 2 + 1];
            float v1x = s_state[(n * KK + k1) * 2 + 0];
            float v1y = s_state[(n * KK + k1) * 2 + 1];
            area2 += v0x * v1y - v1x * v0y;
        }
        float orient = (area2 > 0.f) ? 1.f : ((area2 < 0.f) ? -1.f : 0.f);
        s_orient[n] = orient;

        float alive = s_state[NN * KK * 2 + n];
        float g = alpha[n] / (1.f + __expf(-alive));

        // stable rank of z[n] ascending; slot 0 = frontmost (largest z)
        float zn = s_z[n];
        int rank = 0;
        for (int j = 0; j < NN; j++) {
            float zj = s_z[j];
            rank += (zj < zn || (zj == zn && j < n)) ? 1 : 0;
        }
        int slot = (NN - 1) - rank;
        s_slot2prim[slot] = n;

        int mode = s_mode;
        int sub;
        if (mode == 0)      sub = ((const int*)csg_raw)[n] != 0;
        else if (mode == 1) sub = ((const unsigned char*)csg_raw)[n] != 0;
        else                sub = ((const float*)csg_raw)[n] != 0.f;
        float cs = sub ? 0.f : 1.f;
        s_coef[slot][36] = g;
        s_coef[slot][37] = colors[n * 3 + 0] * cs;
        s_coef[slot][38] = colors[n * 3 + 1] * cs;
        s_coef[slot][39] = colors[n * 3 + 2] * cs;
    }
    __syncthreads();

    // ---- Phase 3: per-edge affine coefficients, slot-ordered, SoA ----
    // u = -s*orient/SOFT*log2(e) = A*gy + B*gx + C ; sigmoid = 1/(1+2^u)
    const float QSCALE = 100.0f * 1.4426950408889634f; // (1/SOFT)*log2(e)
    for (int idx = tid; idx < NN * KK; idx += TPB) {
        int slot = idx / KK;
        int k    = idx - slot * KK;
        int n    = s_slot2prim[slot];
        int k1   = (k + 1) % KK;
        float v0x = s_state[(n * KK + k)  * 2 + 0];
        float v0y = s_state[(n * KK + k)  * 2 + 1];
        float v1x = s_state[(n * KK + k1) * 2 + 0];
        float v1y = s_state[(n * KK + k1) * 2 + 1];
        float ex = v1x - v0x, ey = v1y - v0y;
        float q  = -s_orient[n] * QSCALE;
        s_coef[slot][0  + k] = q * ex;                      // A: coeff of gy
        s_coef[slot][12 + k] = -q * ey;                     // B: coeff of gx
        s_coef[slot][24 + k] = -q * (ex * v0y - ey * v0x);  // C: constant
    }
    __syncthreads();

    // ---- Phase 3.5a: per-(row, slot) JOINT interval cull ----
    // Feasible set {gx : u_k(gx) < CULL_U for all k} is an interval; empty
    // (after SLACK widening) => max per-pixel contribution < 2^-CULL_U.
    const float GX_LO = 0.5f / WW;
    const float GX_HI = (WW - 0.5f) / WW;
    const float SLACK = 0.02f; // ~2.5 px; >> rcp approximation error
    for (int idx = tid; idx < ROWS_PER_BLOCK * NN; idx += TPB) {
        int r = idx >> 7;
        int s = idx & (NN - 1);
        float gyr = (row0 + r + 0.5f) * (1.0f / HH);
        float xlo = GX_LO, xhi = GX_HI;
        #pragma unroll
        for (int k = 0; k < KK; k++) {
            float A = s_coef[s][k];
            float B = s_coef[s][12 + k];
            float C = s_coef[s][24 + k];
            float base = fmaf(A, gyr, C);
            float t = (CULL_U - base) * __builtin_amdgcn_rcpf(B);
            // B>0: gx < t ; B<0: gx > t ; B==0/NaN cases resolve to "no constraint"
            xhi = fminf(xhi, (B > 0.f) ? (t + SLACK) :  1e30f);
            xlo = fmaxf(xlo, (B < 0.f) ? (t - SLACK) : -1e30f);
        }
        s_keep[r][s] = (xlo <= xhi) ? 1 : 0;
    }
    __syncthreads();

    // ---- Phase 3.5b: stable compaction, one wave per row (z order kept) ----
    {
        const int wv = tid >> 6, ln = tid & 63;
        int base = 0;
        #pragma unroll
        for (int half = 0; half < 2; half++) {
            int s = half * 64 + ln;
            bool k = s_keep[wv][s] != 0;
            unsigned long long m = __ballot(k);
            int pre = __popcll(m & ((1ull << ln) - 1ull));
            if (k) s_list[wv][base + pre] = (unsigned char)s;
            base += __popcll(m);
        }
        if (ln == 0) s_cnt[wv] = base;
    }
    __syncthreads();

    // ---- Main: two pixels (same row) per thread; wave = one row ----
    const int wv   = tid >> 6;
    const int lane = tid & 63;
    const int row  = row0 + wv;
    const int px0  = lane * 2;
    const float gy = (row + 0.5f) * (1.0f / HH);
    const float gx = (px0 + 0.5f) * (1.0f / WW);
    const f2 gyv = {gy, gy};
    const f2 gxv = {gx, gx};
    const f2 dxv = {1.0f / WW, 1.0f / WW};
    const f2 loV = {-100.f, -100.f};

    float T0 = 1.f, T1 = 1.f;
    float r0 = 0.f, g0 = 0.f, b0 = 0.f;
    float r1 = 0.f, g1 = 0.f, b1 = 0.f;

    const int cnt = s_cnt[wv];
    int slot = (cnt > 0) ? (int)s_list[wv][0] : 0;
    for (int i = 0; i < cnt; i++) {
        int nslot = (int)s_list[wv][i + 1]; // prefetch (padded; unused on last iter)

        float cf[40];
        const float4* cp = (const float4*)&s_coef[slot][0];
        #pragma unroll
        for (int i4 = 0; i4 < 10; i4++) ((float4*)cf)[i4] = cp[i4]; // ds_read_b128 x10

        const f2* Ap = (const f2*)&cf[0];
        const f2* Bp = (const f2*)&cf[12];
        const f2* Cp = (const f2*)&cf[24];

        f2 q0 = {1.f, 1.f}, q1 = {1.f, 1.f};
        #pragma unroll
        for (int j = 0; j < 6; j++) {
            f2 u0 = __builtin_elementwise_fma(Ap[j], gyv,
                      __builtin_elementwise_fma(Bp[j], gxv, Cp[j]));
            f2 u1 = __builtin_elementwise_fma(Bp[j], dxv, u0); // next pixel in row
            u0 = __builtin_elementwise_max(u0, loV); // forbid exp2 underflow (inf*0=NaN)
            u1 = __builtin_elementwise_max(u1, loV);
            f2 e0, e1;
            e0.x = __builtin_amdgcn_exp2f(u0.x);
            e0.y = __builtin_amdgcn_exp2f(u0.y);
            e1.x = __builtin_amdgcn_exp2f(u1.x);
            e1.y = __builtin_amdgcn_exp2f(u1.y);
            q0 = __builtin_elementwise_fma(q0, e0, q0); // q *= (1 + 2^u)
            q1 = __builtin_elementwise_fma(q1, e1, q1);
        }
        float cov0 = __builtin_amdgcn_rcpf(q0.x * q0.y);
        float cov1 = __builtin_amdgcn_rcpf(q1.x * q1.y);

        float gA = cf[36], cr = cf[37], cg = cf[38], cb = cf[39];
        float a0 = cov0 * gA, a1 = cov1 * gA;
        float w0 = a0 * T0,   w1 = a1 * T1;
        r0 = fmaf(w0, cr, r0);  r1 = fmaf(w1, cr, r1);
        g0 = fmaf(w0, cg, g0);  g1 = fmaf(w1, cg, g1);
        b0 = fmaf(w0, cb, b0);  b1 = fmaf(w1, cb, b1);
        T0 = fmaf(-a0, T0, T0); T1 = fmaf(-a1, T1, T1);

        slot = nslot;
        // wave-coherent early exit: residual contribution <= T < 1e-3
        if (!__any(fmaxf(T0, T1) > 1e-3f)) break;
    }

    size_t o = ((size_t)frame * (HH * WW) + (size_t)row * WW + px0) * 3;
    float2* op = (float2*)(out + o);
    op[0] = make_float2(r0, g0);
    op[1] = make_float2(b0, r1);
    op[2] = make_float2(g1, b1);
}

extern "C" void kernel_launch(void* const* d_in, const int* in_sizes, int n_in,
                              void* d_out, int out_size, void* d_ws, size_t ws_size,
                              hipStream_t stream) {
    const float* traj   = (const float*)d_in[0];
    const float* colors = (const float*)d_in[1];
    const float* alpha  = (const float*)d_in[2];
    const float* zval   = (const float*)d_in[3];
    const void*  csg    = d_in[4];
    float* out = (float*)d_out;

    const int T = in_sizes[0] / STATE_SZ; // 192
    dim3 grid(HH / ROWS_PER_BLOCK, T);    // 32 x 192
    raster_kernel<<<grid, TPB, 0, stream>>>(traj, colors, alpha, zval, csg, out);
}

// Round 6
// 429.953 us; speedup vs baseline: 1.9873x; 1.3106x over previous
//
#include <hip/hip_runtime.h>

// Soft differentiable rasterizer, forward only. Two-kernel structure:
//
// setup_kernel (1 block per frame): stage state, z-rank sort (slot 0 =
//   frontmost), per-edge affine coeffs u = A*gy + B*gx + C (orient/SOFT/log2e
//   folded), JOINT gx-interval cull per (row, slot) -> per-HALF-ROW (64 px)
//   compacted survivor lists. Writes coef[128][40] + cnt[256] + list[256][128]
//   per frame into d_ws.
//
// raster_kernel: 1 wave = 1 half-row, 1 px/thread. Coefficients are
//   wave-uniform: slot index forced scalar via readfirstlane so the 40-float
//   block loads go through the SCALAR cache (s_load), not LDS/VMEM-per-lane.
//   R5 was LDS-pipe bound (160 B broadcast per slot-iter per wave, ~2x VALU
//   demand); this removes main-loop LDS entirely.
//
// cov = prod sigmoid = 1/prod(1+2^u); clamp u >= -100 (inf*0=NaN guard);
// front-to-back transmittance with wave-coherent exit at T < 1e-3.
// Error budget: base 9.8e-4 + cull 128*2^-20 + exit 1e-3 << 8.6e-3 threshold.

#define HH 128
#define WW 128
#define NN 128
#define KK 12
#define TPB 256
#define STATE_SZ (NN * KK * 2 + NN) // 3200
#define CULL_U 20.0f
#define COEF_STRIDE 40              // floats per slot: A[12] B[12] C[12] gc[4]

__global__ __launch_bounds__(TPB) void setup_kernel(
    const float* __restrict__ traj,
    const float* __restrict__ colors,
    const float* __restrict__ alpha,
    const float* __restrict__ zval,
    const void*  __restrict__ csg_raw,
    float* __restrict__ g_coef,         // [T][128][40]
    int* __restrict__ g_cnt,            // [T][256]
    unsigned char* __restrict__ g_list) // [T][256][128]
{
    __shared__ __align__(16) float s_coef[NN][COEF_STRIDE];
    __shared__ float s_state[STATE_SZ];
    __shared__ float s_orient[NN];
    __shared__ float s_z[NN];
    __shared__ int   s_slot2prim[NN];
    __shared__ unsigned long long s_bits[2 * HH][2]; // keep-bits per half-row
    __shared__ unsigned char s_list[2 * HH][NN];
    __shared__ int s_cnt[2 * HH];
    __shared__ int s_mode;

    const int frame = blockIdx.x;
    const int tid   = threadIdx.x;
    const float* st = traj + (size_t)frame * STATE_SZ;

    // ---- stage + csg layout detect ----
    for (int i = tid; i < STATE_SZ; i += TPB) s_state[i] = st[i];
    if (tid < NN) s_z[tid] = zval[tid];
    if (tid == 0) {
        const unsigned char* b = (const unsigned char*)csg_raw;
        const unsigned int*  w = (const unsigned int*)csg_raw;
        int mode = 0; // int32
        bool words01 = true;
        for (int i = 0; i < 32; i++) if (w[i] > 1u) { words01 = false; break; }
        if (!words01) {
            bool bytes01 = true;
            for (int i = 0; i < 128; i++) if (b[i] > 1) { bytes01 = false; break; }
            mode = bytes01 ? 1 : 2;
        }
        s_mode = mode;
    }
    __syncthreads();

    // ---- per-prim: orient, g = alpha*sigmoid(alive), z-rank -> slot ----
    if (tid < NN) {
        const int n = tid;
        float area2 = 0.f;
        #pragma unroll
        for (int k = 0; k < KK; k++) {
            int k1 = (k + 1) % KK;
            float v0x = s_state[(n * KK + k)  * 2 + 0];
            float v0y = s_state[(n * KK + k)  * 2 + 1];
            float v1x = s_state[(n * KK + k1) * 2 + 0];
            float v1y = s_state[(n * KK + k1) * 2 + 1];
            area2 += v0x * v1y - v1x * v0y;
        }
        float orient = (area2 > 0.f) ? 1.f : ((area2 < 0.f) ? -1.f : 0.f);
        s_orient[n] = orient;

        float alive = s_state[NN * KK * 2 + n];
        float g = alpha[n] / (1.f + __expf(-alive));

        float zn = s_z[n];
        int rank = 0;
        for (int j = 0; j < NN; j++) {
            float zj = s_z[j];
            rank += (zj < zn || (zj == zn && j < n)) ? 1 : 0;
        }
        int slot = (NN - 1) - rank; // slot 0 = frontmost (largest z)
        s_slot2prim[slot] = n;

        int mode = s_mode;
        int sub;
        if (mode == 0)      sub = ((const int*)csg_raw)[n] != 0;
        else if (mode == 1) sub = ((const unsigned char*)csg_raw)[n] != 0;
        else                sub = ((const float*)csg_raw)[n] != 0.f;
        float cs = sub ? 0.f : 1.f;
        s_coef[slot][36] = g;
        s_coef[slot][37] = colors[n * 3 + 0] * cs;
        s_coef[slot][38] = colors[n * 3 + 1] * cs;
        s_coef[slot][39] = colors[n * 3 + 2] * cs;
    }
    __syncthreads();

    // ---- edge coefficients (slot-ordered SoA) ----
    const float QSCALE = 100.0f * 1.4426950408889634f;
    for (int idx = tid; idx < NN * KK; idx += TPB) {
        int slot = idx / KK;
        int k    = idx - slot * KK;
        int n    = s_slot2prim[slot];
        int k1   = (k + 1) % KK;
        float v0x = s_state[(n * KK + k)  * 2 + 0];
        float v0y = s_state[(n * KK + k)  * 2 + 1];
        float v1x = s_state[(n * KK + k1) * 2 + 0];
        float v1y = s_state[(n * KK + k1) * 2 + 1];
        float ex = v1x - v0x, ey = v1y - v0y;
        float q  = -s_orient[n] * QSCALE;
        s_coef[slot][0  + k] = q * ex;                      // A
        s_coef[slot][12 + k] = -q * ey;                     // B
        s_coef[slot][24 + k] = -q * (ex * v0y - ey * v0x);  // C
    }
    __syncthreads();

    // ---- joint interval cull per (row, slot); keep bits per half-row ----
    const float GX_LO = 0.5f / WW;
    const float GX_HI = (WW - 0.5f) / WW;
    const float SLACK = 0.02f;
    for (int j = 0; j < (HH * NN) / TPB; j++) {       // 64 iters
        int idx = j * TPB + tid;
        int r = idx >> 7, s = idx & (NN - 1);
        float gyr = (r + 0.5f) * (1.0f / HH);
        float xlo = GX_LO, xhi = GX_HI;
        #pragma unroll
        for (int k = 0; k < KK; k++) {
            float A = s_coef[s][k];
            float B = s_coef[s][12 + k];
            float C = s_coef[s][24 + k];
            float base = fmaf(A, gyr, C);
            float t = (CULL_U - base) * __builtin_amdgcn_rcpf(B);
            xhi = fminf(xhi, (B > 0.f) ? (t + SLACK) :  1e30f);
            xlo = fmaxf(xlo, (B < 0.f) ? (t - SLACK) : -1e30f);
        }
        bool ne = (xlo <= xhi);
        unsigned long long m0 = __ballot(ne && (xlo <= 0.5f)); // left half
        unsigned long long m1 = __ballot(ne && (xhi >= 0.5f)); // right half
        if ((tid & 63) == 0) {
            int word = (s >= 64) ? 1 : 0;
            s_bits[r * 2 + 0][word] = m0;
            s_bits[r * 2 + 1][word] = m1;
        }
    }
    __syncthreads();

    // ---- compaction: thread = half-row, ascending slot = front-to-back ----
    {
        unsigned long long b0 = s_bits[tid][0], b1 = s_bits[tid][1];
        int n = 0;
        while (b0) { int k = __builtin_ctzll(b0); b0 &= b0 - 1; s_list[tid][n++] = (unsigned char)k; }
        while (b1) { int k = __builtin_ctzll(b1); b1 &= b1 - 1; s_list[tid][n++] = (unsigned char)(64 + k); }
        s_cnt[tid] = n;
    }
    __syncthreads();

    // ---- copy out ----
    {
        float* dstc = g_coef + (size_t)frame * (NN * COEF_STRIDE);
        const float* srcc = &s_coef[0][0];
        for (int i = tid; i < NN * COEF_STRIDE; i += TPB) dstc[i] = srcc[i];
        g_cnt[frame * 2 * HH + tid] = s_cnt[tid];
        unsigned int* dstl = (unsigned int*)(g_list + (size_t)frame * (2 * HH * NN));
        const unsigned int* srcl = (const unsigned int*)&s_list[0][0];
        for (int i = tid; i < (2 * HH * NN) / 4; i += TPB) dstl[i] = srcl[i];
    }
}

struct F3 { float x, y, z; };

__global__ __launch_bounds__(TPB) void raster_kernel(
    const float* __restrict__ g_coef,
    const int* __restrict__ g_cnt,
    const unsigned char* __restrict__ g_list,
    float* __restrict__ out)
{
    __shared__ unsigned char s_wlist[4][NN];

    const int tid   = threadIdx.x;
    const int wv    = __builtin_amdgcn_readfirstlane(tid >> 6);
    const int lane  = tid & 63;
    const int frame = blockIdx.y;
    const int half_idx = blockIdx.x * 4 + wv;  // 0..255
    const int row  = half_idx >> 1;
    const int half = half_idx & 1;

    // stage this wave's survivor list into its private LDS strip
    const unsigned char* lst = g_list + ((size_t)frame * 2 * HH + half_idx) * NN;
    if (lane < NN / 4) {
        ((unsigned int*)&s_wlist[wv][0])[lane] = ((const unsigned int*)lst)[lane];
    }
    const int cnt = g_cnt[frame * 2 * HH + half_idx]; // uniform -> s_load

    const int px = half * 64 + lane;
    const float gy = (row + 0.5f) * (1.0f / HH);
    const float gx = (px  + 0.5f) * (1.0f / WW);

    const float* cfr = g_coef + (size_t)frame * (NN * COEF_STRIDE);

    float Tt = 1.f, rr = 0.f, gg = 0.f, bb = 0.f;
    for (int i = 0; i < cnt; i++) {
        int slot = __builtin_amdgcn_readfirstlane((int)s_wlist[wv][i]);
        const float* cf = cfr + slot * COEF_STRIDE; // uniform addr -> scalar loads

        float q = 1.f;
        #pragma unroll
        for (int k = 0; k < KK; k++) {
            float base = fmaf(cf[k], gy, cf[24 + k]);
            float u    = fmaf(cf[12 + k], gx, base);
            u = fmaxf(u, -100.0f);           // exp2 underflow guard (inf*0=NaN)
            q = fmaf(q, __builtin_amdgcn_exp2f(u), q); // q *= 1 + 2^u
        }
        float cov = __builtin_amdgcn_rcpf(q);

        float a = cov * cf[36];
        float w = a * Tt;
        rr = fmaf(w, cf[37], rr);
        gg = fmaf(w, cf[38], gg);
        bb = fmaf(w, cf[39], bb);
        Tt = fmaf(-a, Tt, Tt);

        if (!__any(Tt > 1e-3f)) break;       // residual <= T < 1e-3
    }

    size_t o = ((size_t)frame * (HH * WW) + (size_t)row * WW + px) * 3;
    *(F3*)(out + o) = F3{rr, gg, bb};        // global_store_dwordx3, coalesced
}

extern "C" void kernel_launch(void* const* d_in, const int* in_sizes, int n_in,
                              void* d_out, int out_size, void* d_ws, size_t ws_size,
                              hipStream_t stream) {
    const float* traj   = (const float*)d_in[0];
    const float* colors = (const float*)d_in[1];
    const float* alpha  = (const float*)d_in[2];
    const float* zval   = (const float*)d_in[3];
    const void*  csg    = d_in[4];
    float* out = (float*)d_out;

    const int T = in_sizes[0] / STATE_SZ; // 192

    // d_ws layout
    size_t coef_sz = (size_t)T * NN * COEF_STRIDE * sizeof(float); // 3.93 MB
    size_t cnt_sz  = (size_t)T * 2 * HH * sizeof(int);             // 0.20 MB
    float* g_coef = (float*)d_ws;
    int*   g_cnt  = (int*)((char*)d_ws + coef_sz);
    unsigned char* g_list = (unsigned char*)d_ws + coef_sz + cnt_sz; // 6.29 MB

    setup_kernel<<<T, TPB, 0, stream>>>(traj, colors, alpha, zval, csg,
                                        g_coef, g_cnt, g_list);
    dim3 grid((2 * HH) / 4, T); // 64 x 192, wave = half-row
    raster_kernel<<<grid, TPB, 0, stream>>>(g_coef, g_cnt, g_list, out);
}

// Round 7
// 249.700 us; speedup vs baseline: 3.4219x; 1.7219x over previous
//
#include <hip/hip_runtime.h>

// Soft differentiable rasterizer, forward only. Two-kernel structure:
// setup_kernel (1 block/frame, TPB 1024): z-rank sort, affine edge coeffs,
//   JOINT gx-interval cull per (row,slot) -> compacted per-half-row lists.
// raster_kernel: wave = half-row (64 px), coefficients via SCALAR cache
//   (slot readfirstlane-uniform). R6 proved this is VALU-issue bound
//   (VALUBusy 90%, conflicts 0, occ 70%); R7 packs edge math into
//   v_pk_fma_f32 pairs (48->24 VALU ops/iter) and spends error headroom
//   (absmax pinned at 2^-10 since R2) on tighter cull (U 20->15) and
//   earlier exit (T < 2e-3).

#define HH 128
#define WW 128
#define NN 128
#define KK 12
#define STPB 1024                   // setup block
#define RTPB 256                    // raster block
#define STATE_SZ (NN * KK * 2 + NN) // 3200
#define CULL_U 15.0f
#define COEF_STRIDE 40              // floats per slot: A[12] B[12] C[12] gc[4]

typedef float f2 __attribute__((ext_vector_type(2)));

__global__ __launch_bounds__(STPB) void setup_kernel(
    const float* __restrict__ traj,
    const float* __restrict__ colors,
    const float* __restrict__ alpha,
    const float* __restrict__ zval,
    const void*  __restrict__ csg_raw,
    float* __restrict__ g_coef,         // [T][128][40]
    int* __restrict__ g_cnt,            // [T][256]
    unsigned char* __restrict__ g_list) // [T][256][128]
{
    __shared__ __align__(16) float s_coef[NN][COEF_STRIDE];
    __shared__ float s_state[STATE_SZ];
    __shared__ float s_orient[NN];
    __shared__ float s_z[NN];
    __shared__ int   s_slot2prim[NN];
    __shared__ unsigned long long s_bits[2 * HH][2]; // keep-bits per half-row
    __shared__ unsigned char s_list[2 * HH][NN];
    __shared__ int s_cnt[2 * HH];
    __shared__ int s_mode;

    const int frame = blockIdx.x;
    const int tid   = threadIdx.x;
    const float* st = traj + (size_t)frame * STATE_SZ;

    // ---- stage + csg layout detect ----
    for (int i = tid; i < STATE_SZ; i += STPB) s_state[i] = st[i];
    if (tid < NN) s_z[tid] = zval[tid];
    if (tid == 0) {
        const unsigned char* b = (const unsigned char*)csg_raw;
        const unsigned int*  w = (const unsigned int*)csg_raw;
        int mode = 0; // int32
        bool words01 = true;
        for (int i = 0; i < 32; i++) if (w[i] > 1u) { words01 = false; break; }
        if (!words01) {
            bool bytes01 = true;
            for (int i = 0; i < 128; i++) if (b[i] > 1) { bytes01 = false; break; }
            mode = bytes01 ? 1 : 2;
        }
        s_mode = mode;
    }
    __syncthreads();

    // ---- per-prim: orient, g = alpha*sigmoid(alive), z-rank -> slot ----
    if (tid < NN) {
        const int n = tid;
        float area2 = 0.f;
        #pragma unroll
        for (int k = 0; k < KK; k++) {
            int k1 = (k + 1) % KK;
            float v0x = s_state[(n * KK + k)  * 2 + 0];
            float v0y = s_state[(n * KK + k)  * 2 + 1];
            float v1x = s_state[(n * KK + k1) * 2 + 0];
            float v1y = s_state[(n * KK + k1) * 2 + 1];
            area2 += v0x * v1y - v1x * v0y;
        }
        float orient = (area2 > 0.f) ? 1.f : ((area2 < 0.f) ? -1.f : 0.f);
        s_orient[n] = orient;

        float alive = s_state[NN * KK * 2 + n];
        float g = alpha[n] / (1.f + __expf(-alive));

        float zn = s_z[n];
        int rank = 0;
        for (int j = 0; j < NN; j++) {
            float zj = s_z[j];
            rank += (zj < zn || (zj == zn && j < n)) ? 1 : 0;
        }
        int slot = (NN - 1) - rank; // slot 0 = frontmost (largest z)
        s_slot2prim[slot] = n;

        int mode = s_mode;
        int sub;
        if (mode == 0)      sub = ((const int*)csg_raw)[n] != 0;
        else if (mode == 1) sub = ((const unsigned char*)csg_raw)[n] != 0;
        else                sub = ((const float*)csg_raw)[n] != 0.f;
        float cs = sub ? 0.f : 1.f;
        s_coef[slot][36] = g;
        s_coef[slot][37] = colors[n * 3 + 0] * cs;
        s_coef[slot][38] = colors[n * 3 + 1] * cs;
        s_coef[slot][39] = colors[n * 3 + 2] * cs;
    }
    __syncthreads();

    // ---- edge coefficients (slot-ordered SoA) ----
    const float QSCALE = 100.0f * 1.4426950408889634f;
    for (int idx = tid; idx < NN * KK; idx += STPB) {
        int slot = idx / KK;
        int k    = idx - slot * KK;
        int n    = s_slot2prim[slot];
        int k1   = (k + 1) % KK;
        float v0x = s_state[(n * KK + k)  * 2 + 0];
        float v0y = s_state[(n * KK + k)  * 2 + 1];
        float v1x = s_state[(n * KK + k1) * 2 + 0];
        float v1y = s_state[(n * KK + k1) * 2 + 1];
        float ex = v1x - v0x, ey = v1y - v0y;
        float q  = -s_orient[n] * QSCALE;
        s_coef[slot][0  + k] = q * ex;                      // A
        s_coef[slot][12 + k] = -q * ey;                     // B
        s_coef[slot][24 + k] = -q * (ex * v0y - ey * v0x);  // C
    }
    __syncthreads();

    // ---- joint interval cull per (row, slot); keep bits per half-row ----
    // wave structure: each 64-lane wave covers one fixed row r and s in
    // [0,64) or [64,128) -> ballot gives one 64-bit keep word.
    const float GX_LO = 0.5f / WW;
    const float GX_HI = (WW - 0.5f) / WW;
    const float SLACK = 0.01f;
    for (int j = 0; j < (HH * NN) / STPB; j++) {     // 16 iters
        int idx = j * STPB + tid;
        int r = idx >> 7, s = idx & (NN - 1);
        float gyr = (r + 0.5f) * (1.0f / HH);
        float xlo = GX_LO, xhi = GX_HI;
        #pragma unroll
        for (int k = 0; k < KK; k++) {
            float A = s_coef[s][k];
            float B = s_coef[s][12 + k];
            float C = s_coef[s][24 + k];
            float base = fmaf(A, gyr, C);
            float t = (CULL_U - base) * __builtin_amdgcn_rcpf(B);
            xhi = fminf(xhi, (B > 0.f) ? (t + SLACK) :  1e30f);
            xlo = fmaxf(xlo, (B < 0.f) ? (t - SLACK) : -1e30f);
        }
        bool ne = (xlo <= xhi);
        unsigned long long m0 = __ballot(ne && (xlo <= 0.5f)); // left half
        unsigned long long m1 = __ballot(ne && (xhi >= 0.5f)); // right half
        if ((tid & 63) == 0) {
            int word = (s >= 64) ? 1 : 0;
            s_bits[r * 2 + 0][word] = m0;
            s_bits[r * 2 + 1][word] = m1;
        }
    }
    __syncthreads();

    // ---- compaction: thread = half-row, ascending slot = front-to-back ----
    if (tid < 2 * HH) {
        unsigned long long b0 = s_bits[tid][0], b1 = s_bits[tid][1];
        int n = 0;
        while (b0) { int k = __builtin_ctzll(b0); b0 &= b0 - 1; s_list[tid][n++] = (unsigned char)k; }
        while (b1) { int k = __builtin_ctzll(b1); b1 &= b1 - 1; s_list[tid][n++] = (unsigned char)(64 + k); }
        s_cnt[tid] = n;
    }
    __syncthreads();

    // ---- copy out ----
    {
        float* dstc = g_coef + (size_t)frame * (NN * COEF_STRIDE);
        const float* srcc = &s_coef[0][0];
        for (int i = tid; i < NN * COEF_STRIDE; i += STPB) dstc[i] = srcc[i];
        if (tid < 2 * HH) g_cnt[frame * 2 * HH + tid] = s_cnt[tid];
        unsigned int* dstl = (unsigned int*)(g_list + (size_t)frame * (2 * HH * NN));
        const unsigned int* srcl = (const unsigned int*)&s_list[0][0];
        for (int i = tid; i < (2 * HH * NN) / 4; i += STPB) dstl[i] = srcl[i];
    }
}

struct F3 { float x, y, z; };

__global__ __launch_bounds__(RTPB) void raster_kernel(
    const float* __restrict__ g_coef,
    const int* __restrict__ g_cnt,
    const unsigned char* __restrict__ g_list,
    float* __restrict__ out)
{
    __shared__ unsigned char s_wlist[4][NN];

    const int tid   = threadIdx.x;
    const int wv    = __builtin_amdgcn_readfirstlane(tid >> 6);
    const int lane  = tid & 63;
    const int frame = blockIdx.y;
    const int half_idx = blockIdx.x * 4 + wv;  // 0..255
    const int row  = half_idx >> 1;
    const int half = half_idx & 1;

    // stage this wave's survivor list into its private LDS strip
    const unsigned char* lst = g_list + ((size_t)frame * 2 * HH + half_idx) * NN;
    if (lane < NN / 4) {
        ((unsigned int*)&s_wlist[wv][0])[lane] = ((const unsigned int*)lst)[lane];
    }
    const int cnt = g_cnt[frame * 2 * HH + half_idx]; // uniform -> s_load

    const int px = half * 64 + lane;
    const float gy = (row + 0.5f) * (1.0f / HH);
    const float gx = (px  + 0.5f) * (1.0f / WW);
    const f2 gy2 = {gy, gy};
    const f2 gx2 = {gx, gx};
    const f2 lo2 = {-100.f, -100.f};

    const float* cfr = g_coef + (size_t)frame * (NN * COEF_STRIDE);

    float Tt = 1.f, rr = 0.f, gg = 0.f, bb = 0.f;
    for (int i = 0; i < cnt; i++) {
        int slot = __builtin_amdgcn_readfirstlane((int)s_wlist[wv][i]);
        const float* cf = cfr + slot * COEF_STRIDE; // uniform addr -> scalar loads
        const f2* A2 = (const f2*)(cf);
        const f2* B2 = (const f2*)(cf + 12);
        const f2* C2 = (const f2*)(cf + 24);

        f2 q = {1.f, 1.f};
        #pragma unroll
        for (int j = 0; j < 6; j++) {
            f2 u = __builtin_elementwise_fma(B2[j], gx2,
                     __builtin_elementwise_fma(A2[j], gy2, C2[j]));
            u = __builtin_elementwise_max(u, lo2);   // exp2 underflow guard (inf*0=NaN)
            f2 e;
            e.x = __builtin_amdgcn_exp2f(u.x);
            e.y = __builtin_amdgcn_exp2f(u.y);
            q = __builtin_elementwise_fma(q, e, q);  // q *= 1 + 2^u
        }
        float cov = __builtin_amdgcn_rcpf(q.x * q.y);

        float a = cov * cf[36];
        float w = a * Tt;
        rr = fmaf(w, cf[37], rr);
        gg = fmaf(w, cf[38], gg);
        bb = fmaf(w, cf[39], bb);
        Tt = fmaf(-a, Tt, Tt);

        if (!__any(Tt > 2e-3f)) break;   // residual <= T < 2e-3
    }

    size_t o = ((size_t)frame * (HH * WW) + (size_t)row * WW + px) * 3;
    *(F3*)(out + o) = F3{rr, gg, bb};    // coalesced dwordx3
}

extern "C" void kernel_launch(void* const* d_in, const int* in_sizes, int n_in,
                              void* d_out, int out_size, void* d_ws, size_t ws_size,
                              hipStream_t stream) {
    const float* traj   = (const float*)d_in[0];
    const float* colors = (const float*)d_in[1];
    const float* alpha  = (const float*)d_in[2];
    const float* zval   = (const float*)d_in[3];
    const void*  csg    = d_in[4];
    float* out = (float*)d_out;

    const int T = in_sizes[0] / STATE_SZ; // 192

    // d_ws layout
    size_t coef_sz = (size_t)T * NN * COEF_STRIDE * sizeof(float); // 3.93 MB
    size_t cnt_sz  = (size_t)T * 2 * HH * sizeof(int);             // 0.20 MB
    float* g_coef = (float*)d_ws;
    int*   g_cnt  = (int*)((char*)d_ws + coef_sz);
    unsigned char* g_list = (unsigned char*)d_ws + coef_sz + cnt_sz; // 6.29 MB

    setup_kernel<<<T, STPB, 0, stream>>>(traj, colors, alpha, zval, csg,
                                         g_coef, g_cnt, g_list);
    dim3 grid((2 * HH) / 4, T); // 64 x 192, wave = half-row
    raster_kernel<<<grid, RTPB, 0, stream>>>(g_coef, g_cnt, g_list, out);
}